// Round 17
// baseline (128.231 us; speedup 1.0000x reference)
//
#include <hip/hip_runtime.h>

#define BATCH 65536
#define NT 256
#define NTG 512
#define MFMA __builtin_amdgcn_mfma_f32_16x16x32_bf16

typedef short bf16x8 __attribute__((ext_vector_type(8)));
typedef float f32x4 __attribute__((ext_vector_type(4)));
typedef unsigned short u16x8 __attribute__((ext_vector_type(8)));
typedef unsigned short u16x4 __attribute__((ext_vector_type(4)));

__device__ __forceinline__ float sigmoidf_(float x) { return 1.0f / (1.0f + __expf(-x)); }
__device__ __forceinline__ float tanhf_(float x) { return 2.0f / (1.0f + __expf(-2.0f * x)) - 1.0f; }
__device__ __forceinline__ unsigned short f2b(float f) {
  union { float f; unsigned int u; } v; v.f = f;
  unsigned int r = (v.u + 0x7FFFu + ((v.u >> 16) & 1u)) >> 16;
  return (unsigned short)r;
}
__device__ __forceinline__ float b2f(unsigned short u) {
  return __uint_as_float(((unsigned int)u) << 16);
}
__device__ __forceinline__ bf16x8 cvt8(float4 a, float4 b) {
  union { unsigned short u[8]; bf16x8 v; } t;
  t.u[0] = f2b(a.x); t.u[1] = f2b(a.y); t.u[2] = f2b(a.z); t.u[3] = f2b(a.w);
  t.u[4] = f2b(b.x); t.u[5] = f2b(b.y); t.u[6] = f2b(b.z); t.u[7] = f2b(b.w);
  return t.v;
}

// ---------------- k_front: conv1+conv2 (blocks 0..1023, bf16 obs LDS)
//                  + prep (blocks 1024..1743)  [R15 proven] ----------------
#define OSTR 149
#define PSTR 146
__global__ __launch_bounds__(NT) void k_front(
    const float* __restrict__ obs, const float* __restrict__ w1,
    const float* __restrict__ b1, const float* __restrict__ w2,
    const float* __restrict__ b2, unsigned short* __restrict__ c2b,
    const float* __restrict__ W0, const float* __restrict__ W1,
    const float* __restrict__ W2, const float* __restrict__ W3,
    const float* __restrict__ W4, const float* __restrict__ W5,
    const float* __restrict__ W6, const float* __restrict__ W7,
    const float* __restrict__ bi0, const float* __restrict__ bi1,
    const float* __restrict__ bi2, const float* __restrict__ bi3,
    const float* __restrict__ bh0, const float* __restrict__ bh1,
    const float* __restrict__ bh2, const float* __restrict__ bh3,
    const float* __restrict__ aw1, const float* __restrict__ cw1,
    const float* __restrict__ w3s,
    unsigned short* __restrict__ wsW, unsigned short* __restrict__ wsH,
    unsigned short* __restrict__ wsW3, float* __restrict__ wsB) {
  const int tid = threadIdx.x;
  const int b = blockIdx.x;

  if (b >= 1024) {
    const int pb = b - 1024;
    const int y = pb / 48;
    const int i = (pb % 48) * NT + tid;
    if (y < 8) {
      if (i >= 12288) return;
      const float* src = (y == 0) ? W0 : (y == 1) ? W1 : (y == 2) ? W2 : (y == 3) ? W3
                       : (y == 4) ? W4 : (y == 5) ? W5 : (y == 6) ? W6 : W7;
      const int c = y >> 1, p = y & 1;
      const int j = i >> 6, k = i & 63;
      const int g = j >> 6, jrow = j & 63;
      const int jt = jrow >> 4, r16i = jrow & 15;
      const int kseg = k >> 5, kgv = (k & 31) >> 3, e = k & 7;
      const int lane = kgv * 16 + r16i;
      const int q = g * 4 + p * 2 + kseg;
      wsW[c * 24576 + ((jt * 12 + q) * 64 + lane) * 8 + e] = f2b(src[i]);
    } else if (y == 8) {
      if (i < 4096) wsH[i] = f2b(aw1[i]);
    } else if (y == 9) {
      if (i < 4096) wsH[4096 + i] = f2b(cw1[i]);
    } else if (y == 10) {
      if (i < 8192) wsW3[i] = f2b(w3s[i]);
    } else {
      const int c = y - 11;
      if (i < 256) {
        const float* bi = (c == 0) ? bi0 : (c == 1) ? bi1 : (c == 2) ? bi2 : bi3;
        const float* bh = (c == 0) ? bh0 : (c == 1) ? bh1 : (c == 2) ? bh2 : bh3;
        const int j = i & 63, g = i >> 6;
        float v = (g == 0) ? bi[j] + bh[j]
                : (g == 1) ? bi[64 + j] + bh[64 + j]
                : (g == 2) ? bi[128 + j] : bh[128 + j];
        wsB[c * 256 + i] = v;
      }
    }
    return;
  }

  __shared__ unsigned short obs_b[64 * OSTR];   // 19.1KB
  __shared__ unsigned short pooled[64 * PSTR];  // 18.7KB
  const int lane = tid & 63;
  const int wave = tid >> 6;
  const int m_base = b * 64;

  {
    const float4* src = (const float4*)(obs + (size_t)m_base * 147);
#pragma unroll 1
    for (int i = tid; i < 2352; i += NT) {
      const float4 v = src[i];
      int idx = i * 4;
      int s = idx / 147;
      int c = idx - s * 147;
      obs_b[s * OSTR + c] = f2b(v.x);
      if (++c == 147) { c = 0; ++s; } obs_b[s * OSTR + c] = f2b(v.y);
      if (++c == 147) { c = 0; ++s; } obs_b[s * OSTR + c] = f2b(v.z);
      if (++c == 147) { c = 0; ++s; } obs_b[s * OSTR + c] = f2b(v.w);
    }
  }
  __syncthreads();

  if (wave < 3) {
    const int ph = wave, s = lane;
    float r[3][21];
#pragma unroll
    for (int rr = 0; rr < 3; ++rr)
#pragma unroll
      for (int i = 0; i < 21; ++i) r[rr][i] = b2f(obs_b[s * OSTR + (2 * ph + rr) * 21 + i]);
#pragma unroll 1
    for (int oc = 0; oc < 16; ++oc) {
      float wv[12];
#pragma unroll
      for (int i = 0; i < 12; ++i) wv[i] = w1[oc * 12 + i];
      const float bias = b1[oc];
#pragma unroll
      for (int pw = 0; pw < 3; ++pw) {
        float m = 0.0f;
#pragma unroll
        for (int dh = 0; dh < 2; ++dh)
#pragma unroll
          for (int dw = 0; dw < 2; ++dw) {
            float acc = bias;
#pragma unroll
            for (int kh = 0; kh < 2; ++kh)
#pragma unroll
              for (int kw = 0; kw < 2; ++kw)
#pragma unroll
                for (int c = 0; c < 3; ++c)
                  acc += r[dh + kh][(2 * pw + dw + kw) * 3 + c] * wv[c * 4 + kh * 2 + kw];
            m = fmaxf(m, fmaxf(acc, 0.0f));
          }
        pooled[s * PSTR + oc * 9 + ph * 3 + pw] = f2b(m);
      }
    }
  }
  __syncthreads();

  {
    const int g = wave, s = lane;
    const int ocb = g * 8;
    float acc[8][4];
#pragma unroll
    for (int u = 0; u < 8; ++u) {
      const float bb = b2[ocb + u];
      acc[u][0] = bb; acc[u][1] = bb; acc[u][2] = bb; acc[u][3] = bb;
    }
#pragma unroll 1
    for (int ic = 0; ic < 16; ++ic) {
      float p9[9];
#pragma unroll
      for (int p = 0; p < 9; ++p) p9[p] = b2f(pooled[s * PSTR + ic * 9 + p]);
#pragma unroll
      for (int u = 0; u < 8; ++u) {
        float w[4];
#pragma unroll
        for (int i = 0; i < 4; ++i) w[i] = w2[((ocb + u) * 16 + ic) * 4 + i];
#pragma unroll
        for (int oh = 0; oh < 2; ++oh)
#pragma unroll
          for (int ow = 0; ow < 2; ++ow)
            acc[u][oh * 2 + ow] += p9[(oh + 0) * 3 + (ow + 0)] * w[0] +
                                   p9[(oh + 0) * 3 + (ow + 1)] * w[1] +
                                   p9[(oh + 1) * 3 + (ow + 0)] * w[2] +
                                   p9[(oh + 1) * 3 + (ow + 1)] * w[3];
      }
    }
    unsigned short ob[32];
#pragma unroll
    for (int u = 0; u < 8; ++u)
#pragma unroll
      for (int p = 0; p < 4; ++p) ob[u * 4 + p] = f2b(fmaxf(acc[u][p], 0.0f));
#pragma unroll
    for (int i = 0; i < 4; ++i)
      *(u16x8*)(c2b + (size_t)(m_base + s) * 128 + g * 32 + 8 * i) = *(const u16x8*)(ob + 8 * i);
  }
}

// ---------------- fused: conv3-GEMM + 4 GRU cells + heads ----------------
// R13/R15 structure; ONLY change: next-cell weight loads ISSUED before the
// first barrier of the staging pair (short live range, ~24 extra VGPR across
// one barrier — NOT R8's loop-long live range), so L2 latency hides under the
// barrier drain instead of being exposed after it.
#define XSTR 88
__global__ __launch_bounds__(NTG, 4) void k_gru(
    const unsigned short* __restrict__ c2b,
    const float* __restrict__ memF,
    const unsigned short* __restrict__ wsW,
    const unsigned short* __restrict__ wsW3,
    const float* __restrict__ wsB,
    const unsigned short* __restrict__ wsH,
    const float* __restrict__ b3,
    const float* __restrict__ ab1, const float* __restrict__ cb1,
    const float* __restrict__ aw2, const float* __restrict__ ab2,
    const float* __restrict__ cw2, const float* __restrict__ cb2,
    float* __restrict__ out) {
  __shared__ unsigned short wlds[24576];      // 48KB
  __shared__ unsigned short xls[128 * XSTR];  // 22.5KB
  const int tid = threadIdx.x;
  const int lane = tid & 63;
  const int wave = tid >> 6;
  const int r16 = lane & 15;
  const int kg = lane >> 4;
  const int wbase = wave * 16;
  const int m_base = blockIdx.x * 128 + wbase;
  float* outMem = out + (size_t)4 * BATCH;

  float4 wst[6];
  {
    const float4* wsrc = (const float4*)wsW;
#pragma unroll
    for (int r = 0; r < 6; ++r) wst[r] = wsrc[r * NTG + tid];
  }
  bf16x8 a0[4];
  {
    const unsigned short* ap = c2b + (size_t)(m_base + r16) * 128 + kg * 8;
#pragma unroll
    for (int f = 0; f < 4; ++f) a0[f] = *(const bf16x8*)(ap + f * 32);
  }
  float4 hraw[4];
  {
    const float* hp = memF + (size_t)(m_base + r16) * 256 + kg * 8;
    hraw[0] = *(const float4*)(hp);
    hraw[1] = *(const float4*)(hp + 4);
    hraw[2] = *(const float4*)(hp + 32);
    hraw[3] = *(const float4*)(hp + 36);
  }

#pragma unroll
  for (int n = 0; n < 4; ++n) {
    const unsigned short* bp = wsW3 + (size_t)(n * 16 + r16) * 128 + kg * 8;
    f32x4 q0 = (f32x4)(0.0f);
#pragma unroll
    for (int f = 0; f < 4; ++f) {
      bf16x8 bb = *(const bf16x8*)(bp + f * 32);
      q0 = MFMA(bb, a0[f], q0, 0, 0, 0);
    }
    const f32x4 b4 = *(const f32x4*)(b3 + n * 16 + kg * 4);
    u16x4 xo;
#pragma unroll
    for (int q = 0; q < 4; ++q) xo[q] = f2b(fmaxf(q0[q] + b4[q], 0.0f));
    *(u16x4*)(xls + (wbase + r16) * XSTR + n * 16 + kg * 4) = xo;
  }
  {
    float4* wd = (float4*)wlds;
#pragma unroll
    for (int r = 0; r < 6; ++r) wd[r * NTG + tid] = wst[r];
  }
  __syncthreads();

#pragma unroll 1
  for (int c = 0; c < 4; ++c) {
    const int co = c * 64;
    const float* bcp = wsB + c * 256;
    bf16x8 ax0, ax1, ah0, ah1;
    {
      const unsigned short* xp = xls + (wbase + r16) * XSTR + kg * 8;
      ax0 = *(const bf16x8*)(xp);
      ax1 = *(const bf16x8*)(xp + 32);
    }
    ah0 = cvt8(make_float4(hraw[0].x, hraw[0].y, hraw[0].z, hraw[0].w),
               make_float4(hraw[1].x, hraw[1].y, hraw[1].z, hraw[1].w));
    ah1 = cvt8(make_float4(hraw[2].x, hraw[2].y, hraw[2].z, hraw[2].w),
               make_float4(hraw[3].x, hraw[3].y, hraw[3].z, hraw[3].w));
    if (c < 3) {
      const float* hp = memF + (size_t)(m_base + r16) * 256 + (c + 1) * 64 + kg * 8;
      hraw[0] = *(const float4*)(hp);
      hraw[1] = *(const float4*)(hp + 4);
      hraw[2] = *(const float4*)(hp + 32);
      hraw[3] = *(const float4*)(hp + 36);
    }
    const unsigned short* wl = wlds + lane * 8;
#pragma unroll 1
    for (int jt = 0; jt < 4; ++jt) {
      const unsigned short* wjt = wl + jt * 6144;
      bf16x8 xr0 = *(const bf16x8*)(wjt);
      bf16x8 xr1 = *(const bf16x8*)(wjt + 512);
      bf16x8 hr0 = *(const bf16x8*)(wjt + 1024);
      bf16x8 hr1 = *(const bf16x8*)(wjt + 1536);
      bf16x8 xz0 = *(const bf16x8*)(wjt + 2048);
      bf16x8 xz1 = *(const bf16x8*)(wjt + 2560);
      bf16x8 hz0 = *(const bf16x8*)(wjt + 3072);
      bf16x8 hz1 = *(const bf16x8*)(wjt + 3584);
      bf16x8 xn0 = *(const bf16x8*)(wjt + 4096);
      bf16x8 xn1 = *(const bf16x8*)(wjt + 4608);
      bf16x8 hn0 = *(const bf16x8*)(wjt + 5120);
      bf16x8 hn1 = *(const bf16x8*)(wjt + 5632);
      f32x4 sr = (f32x4)(0.0f), sz = (f32x4)(0.0f), sn = (f32x4)(0.0f), tn = (f32x4)(0.0f);
      sr = MFMA(xr0, ax0, sr, 0, 0, 0);
      sr = MFMA(xr1, ax1, sr, 0, 0, 0);
      sr = MFMA(hr0, ah0, sr, 0, 0, 0);
      sr = MFMA(hr1, ah1, sr, 0, 0, 0);
      sz = MFMA(xz0, ax0, sz, 0, 0, 0);
      sz = MFMA(xz1, ax1, sz, 0, 0, 0);
      sz = MFMA(hz0, ah0, sz, 0, 0, 0);
      sz = MFMA(hz1, ah1, sz, 0, 0, 0);
      sn = MFMA(xn0, ax0, sn, 0, 0, 0);
      sn = MFMA(xn1, ax1, sn, 0, 0, 0);
      tn = MFMA(hn0, ah0, tn, 0, 0, 0);
      tn = MFMA(hn1, ah1, tn, 0, 0, 0);
      const int jb = jt * 16 + kg * 4;
      const f32x4 ho4 = *(const f32x4*)(memF + (size_t)(m_base + r16) * 256 + co + jb);
      const f32x4 rb4 = *(const f32x4*)(bcp + jb);
      const f32x4 zb4 = *(const f32x4*)(bcp + 64 + jb);
      const f32x4 ib4 = *(const f32x4*)(bcp + 128 + jb);
      const f32x4 hb4 = *(const f32x4*)(bcp + 192 + jb);
      f32x4 nhv;
      u16x4 xo;
#pragma unroll
      for (int q = 0; q < 4; ++q) {
        const float rg = sigmoidf_(sr[q] + rb4[q]);
        const float zg = sigmoidf_(sz[q] + zb4[q]);
        const float ng = tanhf_((sn[q] + ib4[q]) + rg * (tn[q] + hb4[q]));
        const float nh = (1.0f - zg) * ng + zg * ho4[q];
        nhv[q] = nh;
        xo[q] = f2b(nh);
      }
      *(f32x4*)(outMem + (size_t)(m_base + r16) * 256 + co + jb) = nhv;
      *(u16x4*)(xls + (wbase + r16) * XSTR + jb) = xo;
    }
    if (c < 3) {
      // issue loads BEFORE the barrier: latency overlaps barrier drain
      float4 wnx[6];
      const float4* wsrc = (const float4*)(wsW + (size_t)(c + 1) * 24576);
#pragma unroll
      for (int r = 0; r < 6; ++r) wnx[r] = wsrc[r * NTG + tid];
      __syncthreads();
      float4* wd = (float4*)wlds;
#pragma unroll
      for (int r = 0; r < 6; ++r) wd[r * NTG + tid] = wnx[r];
      __syncthreads();
    }
  }

  // ---- heads ----
  bf16x8 ex0, ex1;
  {
    const unsigned short* xp = xls + (wbase + r16) * XSTR + kg * 8;
    ex0 = *(const bf16x8*)(xp);
    ex1 = *(const bf16x8*)(xp + 32);
  }
  f32x4 ha[8];
#pragma unroll
  for (int n = 0; n < 8; ++n) ha[n] = (f32x4)(0.0f);
#pragma unroll
  for (int n = 0; n < 8; ++n) {
    const unsigned short* wp = wsH + (size_t)(n * 16 + r16) * 64 + kg * 8;
    bf16x8 b0 = *(const bf16x8*)(wp);
    bf16x8 b1 = *(const bf16x8*)(wp + 32);
    ha[n] = MFMA(b0, ex0, ha[n], 0, 0, 0);
    ha[n] = MFMA(b1, ex1, ha[n], 0, 0, 0);
  }
  float l0 = 0.0f, l1 = 0.0f, l2 = 0.0f, vv = 0.0f;
  const int jb0 = kg * 4;
#pragma unroll
  for (int t = 0; t < 4; ++t) {
    const f32x4 ba4 = *(const f32x4*)(ab1 + t * 16 + jb0);
    const f32x4 w0 = *(const f32x4*)(aw2 + t * 16 + jb0);
    const f32x4 w1v = *(const f32x4*)(aw2 + 64 + t * 16 + jb0);
    const f32x4 w2v = *(const f32x4*)(aw2 + 128 + t * 16 + jb0);
    const f32x4 bc4 = *(const f32x4*)(cb1 + t * 16 + jb0);
    const f32x4 wc4 = *(const f32x4*)(cw2 + t * 16 + jb0);
#pragma unroll
    for (int q = 0; q < 4; ++q) {
      const float av = fmaxf(ha[t][q] + ba4[q], 0.0f);
      const float cv = fmaxf(ha[t + 4][q] + bc4[q], 0.0f);
      l0 += av * w0[q]; l1 += av * w1v[q]; l2 += av * w2v[q];
      vv += cv * wc4[q];
    }
  }
  l0 += __shfl_xor(l0, 16); l0 += __shfl_xor(l0, 32);
  l1 += __shfl_xor(l1, 16); l1 += __shfl_xor(l1, 32);
  l2 += __shfl_xor(l2, 16); l2 += __shfl_xor(l2, 32);
  vv += __shfl_xor(vv, 16); vv += __shfl_xor(vv, 32);
  if (kg == 0) {
    const int sq = m_base + r16;
    const float g0 = l0 + ab2[0], g1 = l1 + ab2[1], g2 = l2 + ab2[2];
    const float mx = fmaxf(g0, fmaxf(g1, g2));
    const float lse = mx + __logf(__expf(g0 - mx) + __expf(g1 - mx) + __expf(g2 - mx));
    out[(size_t)sq * 3 + 0] = g0 - lse;
    out[(size_t)sq * 3 + 1] = g1 - lse;
    out[(size_t)sq * 3 + 2] = g2 - lse;
    out[(size_t)3 * BATCH + sq] = vv + cb2[0];
  }
}

extern "C" void kernel_launch(void* const* d_in, const int* in_sizes, int n_in,
                              void* d_out, int out_size, void* d_ws, size_t ws_size,
                              hipStream_t stream) {
  (void)in_sizes; (void)n_in; (void)out_size; (void)ws_size;
  const float* obs = (const float*)d_in[0];
  const float* mem = (const float*)d_in[1];
  const float* w1 = (const float*)d_in[2];
  const float* b1 = (const float*)d_in[3];
  const float* w2 = (const float*)d_in[4];
  const float* b2 = (const float*)d_in[5];
  const float* w3 = (const float*)d_in[6];
  const float* b3 = (const float*)d_in[7];
  const float* gw[16];
  for (int i = 0; i < 16; ++i) gw[i] = (const float*)d_in[8 + i];
  const float* aw1 = (const float*)d_in[24];
  const float* ab1 = (const float*)d_in[25];
  const float* aw2 = (const float*)d_in[26];
  const float* ab2 = (const float*)d_in[27];
  const float* cw1 = (const float*)d_in[28];
  const float* cb1 = (const float*)d_in[29];
  const float* cw2 = (const float*)d_in[30];
  const float* cb2 = (const float*)d_in[31];

  float* out = (float*)d_out;

  unsigned short* c2b = (unsigned short*)d_ws;                 // 128*B u16
  unsigned short* wsW = c2b + (size_t)128 * BATCH;             // 4*24576
  unsigned short* wsH = wsW + 98304;                           // 8192
  unsigned short* wsW3 = wsH + 8192;                           // 8192
  float* wsB = (float*)(wsW3 + 8192);                          // 1024 f32

  hipLaunchKernelGGL(k_front, dim3(1024 + 720), dim3(NT), 0, stream,
                     obs, w1, b1, w2, b2, c2b,
                     gw[0], gw[1], gw[4], gw[5], gw[8], gw[9], gw[12], gw[13],
                     gw[2], gw[6], gw[10], gw[14],
                     gw[3], gw[7], gw[11], gw[15],
                     aw1, cw1, w3, wsW, wsH, wsW3, wsB);
  hipLaunchKernelGGL(k_gru, dim3(BATCH / 128), dim3(NTG), 0, stream,
                     c2b, mem, wsW, wsW3, wsB, wsH, b3,
                     ab1, cb1, aw2, ab2, cw2, cb2, out);
}

// Round 18
// 107.583 us; speedup vs baseline: 1.1919x; 1.1919x over previous
//
#include <hip/hip_runtime.h>

#define BATCH 65536
#define NT 256
#define NTG 512
#define MFMA __builtin_amdgcn_mfma_f32_16x16x32_bf16

typedef short bf16x8 __attribute__((ext_vector_type(8)));
typedef float f32x4 __attribute__((ext_vector_type(4)));
typedef unsigned short u16x8 __attribute__((ext_vector_type(8)));
typedef unsigned short u16x4 __attribute__((ext_vector_type(4)));

__device__ __forceinline__ float sigmoidf_(float x) { return 1.0f / (1.0f + __expf(-x)); }
__device__ __forceinline__ float tanhf_(float x) { return 2.0f / (1.0f + __expf(-2.0f * x)) - 1.0f; }
__device__ __forceinline__ unsigned short f2b(float f) {
  union { float f; unsigned int u; } v; v.f = f;
  unsigned int r = (v.u + 0x7FFFu + ((v.u >> 16) & 1u)) >> 16;
  return (unsigned short)r;
}
__device__ __forceinline__ float b2f(unsigned short u) {
  return __uint_as_float(((unsigned int)u) << 16);
}
__device__ __forceinline__ bf16x8 cvt8(float4 a, float4 b) {
  union { unsigned short u[8]; bf16x8 v; } t;
  t.u[0] = f2b(a.x); t.u[1] = f2b(a.y); t.u[2] = f2b(a.z); t.u[3] = f2b(a.w);
  t.u[4] = f2b(b.x); t.u[5] = f2b(b.y); t.u[6] = f2b(b.z); t.u[7] = f2b(b.w);
  return t.v;
}

// ---------------- k_front: conv1+conv2 (blocks 0..1023, bf16 obs LDS)
//                  + prep (blocks 1024..1743)  [R15 proven optimum] ----------------
#define OSTR 149
#define PSTR 146
__global__ __launch_bounds__(NT) void k_front(
    const float* __restrict__ obs, const float* __restrict__ w1,
    const float* __restrict__ b1, const float* __restrict__ w2,
    const float* __restrict__ b2, unsigned short* __restrict__ c2b,
    const float* __restrict__ W0, const float* __restrict__ W1,
    const float* __restrict__ W2, const float* __restrict__ W3,
    const float* __restrict__ W4, const float* __restrict__ W5,
    const float* __restrict__ W6, const float* __restrict__ W7,
    const float* __restrict__ bi0, const float* __restrict__ bi1,
    const float* __restrict__ bi2, const float* __restrict__ bi3,
    const float* __restrict__ bh0, const float* __restrict__ bh1,
    const float* __restrict__ bh2, const float* __restrict__ bh3,
    const float* __restrict__ aw1, const float* __restrict__ cw1,
    const float* __restrict__ w3s,
    unsigned short* __restrict__ wsW, unsigned short* __restrict__ wsH,
    unsigned short* __restrict__ wsW3, float* __restrict__ wsB) {
  const int tid = threadIdx.x;
  const int b = blockIdx.x;

  if (b >= 1024) {
    const int pb = b - 1024;
    const int y = pb / 48;
    const int i = (pb % 48) * NT + tid;
    if (y < 8) {
      if (i >= 12288) return;
      const float* src = (y == 0) ? W0 : (y == 1) ? W1 : (y == 2) ? W2 : (y == 3) ? W3
                       : (y == 4) ? W4 : (y == 5) ? W5 : (y == 6) ? W6 : W7;
      const int c = y >> 1, p = y & 1;
      const int j = i >> 6, k = i & 63;
      const int g = j >> 6, jrow = j & 63;
      const int jt = jrow >> 4, r16i = jrow & 15;
      const int kseg = k >> 5, kgv = (k & 31) >> 3, e = k & 7;
      const int lane = kgv * 16 + r16i;
      const int q = g * 4 + p * 2 + kseg;
      wsW[c * 24576 + ((jt * 12 + q) * 64 + lane) * 8 + e] = f2b(src[i]);
    } else if (y == 8) {
      if (i < 4096) wsH[i] = f2b(aw1[i]);
    } else if (y == 9) {
      if (i < 4096) wsH[4096 + i] = f2b(cw1[i]);
    } else if (y == 10) {
      if (i < 8192) wsW3[i] = f2b(w3s[i]);
    } else {
      const int c = y - 11;
      if (i < 256) {
        const float* bi = (c == 0) ? bi0 : (c == 1) ? bi1 : (c == 2) ? bi2 : bi3;
        const float* bh = (c == 0) ? bh0 : (c == 1) ? bh1 : (c == 2) ? bh2 : bh3;
        const int j = i & 63, g = i >> 6;
        float v = (g == 0) ? bi[j] + bh[j]
                : (g == 1) ? bi[64 + j] + bh[64 + j]
                : (g == 2) ? bi[128 + j] : bh[128 + j];
        wsB[c * 256 + i] = v;
      }
    }
    return;
  }

  __shared__ unsigned short obs_b[64 * OSTR];   // 19.1KB
  __shared__ unsigned short pooled[64 * PSTR];  // 18.7KB
  const int lane = tid & 63;
  const int wave = tid >> 6;
  const int m_base = b * 64;

  {
    const float4* src = (const float4*)(obs + (size_t)m_base * 147);
#pragma unroll 1
    for (int i = tid; i < 2352; i += NT) {
      const float4 v = src[i];
      int idx = i * 4;
      int s = idx / 147;
      int c = idx - s * 147;
      obs_b[s * OSTR + c] = f2b(v.x);
      if (++c == 147) { c = 0; ++s; } obs_b[s * OSTR + c] = f2b(v.y);
      if (++c == 147) { c = 0; ++s; } obs_b[s * OSTR + c] = f2b(v.z);
      if (++c == 147) { c = 0; ++s; } obs_b[s * OSTR + c] = f2b(v.w);
    }
  }
  __syncthreads();

  if (wave < 3) {
    const int ph = wave, s = lane;
    float r[3][21];
#pragma unroll
    for (int rr = 0; rr < 3; ++rr)
#pragma unroll
      for (int i = 0; i < 21; ++i) r[rr][i] = b2f(obs_b[s * OSTR + (2 * ph + rr) * 21 + i]);
#pragma unroll 1
    for (int oc = 0; oc < 16; ++oc) {
      float wv[12];
#pragma unroll
      for (int i = 0; i < 12; ++i) wv[i] = w1[oc * 12 + i];
      const float bias = b1[oc];
#pragma unroll
      for (int pw = 0; pw < 3; ++pw) {
        float m = 0.0f;
#pragma unroll
        for (int dh = 0; dh < 2; ++dh)
#pragma unroll
          for (int dw = 0; dw < 2; ++dw) {
            float acc = bias;
#pragma unroll
            for (int kh = 0; kh < 2; ++kh)
#pragma unroll
              for (int kw = 0; kw < 2; ++kw)
#pragma unroll
                for (int c = 0; c < 3; ++c)
                  acc += r[dh + kh][(2 * pw + dw + kw) * 3 + c] * wv[c * 4 + kh * 2 + kw];
            m = fmaxf(m, fmaxf(acc, 0.0f));
          }
        pooled[s * PSTR + oc * 9 + ph * 3 + pw] = f2b(m);
      }
    }
  }
  __syncthreads();

  {
    const int g = wave, s = lane;
    const int ocb = g * 8;
    float acc[8][4];
#pragma unroll
    for (int u = 0; u < 8; ++u) {
      const float bb = b2[ocb + u];
      acc[u][0] = bb; acc[u][1] = bb; acc[u][2] = bb; acc[u][3] = bb;
    }
#pragma unroll 1
    for (int ic = 0; ic < 16; ++ic) {
      float p9[9];
#pragma unroll
      for (int p = 0; p < 9; ++p) p9[p] = b2f(pooled[s * PSTR + ic * 9 + p]);
#pragma unroll
      for (int u = 0; u < 8; ++u) {
        float w[4];
#pragma unroll
        for (int i = 0; i < 4; ++i) w[i] = w2[((ocb + u) * 16 + ic) * 4 + i];
#pragma unroll
        for (int oh = 0; oh < 2; ++oh)
#pragma unroll
          for (int ow = 0; ow < 2; ++ow)
            acc[u][oh * 2 + ow] += p9[(oh + 0) * 3 + (ow + 0)] * w[0] +
                                   p9[(oh + 0) * 3 + (ow + 1)] * w[1] +
                                   p9[(oh + 1) * 3 + (ow + 0)] * w[2] +
                                   p9[(oh + 1) * 3 + (ow + 1)] * w[3];
      }
    }
    unsigned short ob[32];
#pragma unroll
    for (int u = 0; u < 8; ++u)
#pragma unroll
      for (int p = 0; p < 4; ++p) ob[u * 4 + p] = f2b(fmaxf(acc[u][p], 0.0f));
#pragma unroll
    for (int i = 0; i < 4; ++i)
      *(u16x8*)(c2b + (size_t)(m_base + s) * 128 + g * 32 + 8 * i) = *(const u16x8*)(ob + 8 * i);
  }
}

// ---------------- fused: conv3-GEMM + 4 GRU cells + heads (R13/R15 proven) ----------------
// Weight staging MUST be the synchronous barrier-pair copy: R8/R16/R17 all
// proved that register-carried state across __syncthreads spills to scratch
// (+75MB write each time) at this occupancy.
#define XSTR 88
__global__ __launch_bounds__(NTG, 4) void k_gru(
    const unsigned short* __restrict__ c2b,
    const float* __restrict__ memF,
    const unsigned short* __restrict__ wsW,
    const unsigned short* __restrict__ wsW3,
    const float* __restrict__ wsB,
    const unsigned short* __restrict__ wsH,
    const float* __restrict__ b3,
    const float* __restrict__ ab1, const float* __restrict__ cb1,
    const float* __restrict__ aw2, const float* __restrict__ ab2,
    const float* __restrict__ cw2, const float* __restrict__ cb2,
    float* __restrict__ out) {
  __shared__ unsigned short wlds[24576];      // 48KB
  __shared__ unsigned short xls[128 * XSTR];  // 22.5KB
  const int tid = threadIdx.x;
  const int lane = tid & 63;
  const int wave = tid >> 6;
  const int r16 = lane & 15;
  const int kg = lane >> 4;
  const int wbase = wave * 16;
  const int m_base = blockIdx.x * 128 + wbase;
  float* outMem = out + (size_t)4 * BATCH;

  float4 wst[6];
  {
    const float4* wsrc = (const float4*)wsW;
#pragma unroll
    for (int r = 0; r < 6; ++r) wst[r] = wsrc[r * NTG + tid];
  }
  bf16x8 a0[4];
  {
    const unsigned short* ap = c2b + (size_t)(m_base + r16) * 128 + kg * 8;
#pragma unroll
    for (int f = 0; f < 4; ++f) a0[f] = *(const bf16x8*)(ap + f * 32);
  }
  float4 hraw[4];
  {
    const float* hp = memF + (size_t)(m_base + r16) * 256 + kg * 8;
    hraw[0] = *(const float4*)(hp);
    hraw[1] = *(const float4*)(hp + 4);
    hraw[2] = *(const float4*)(hp + 32);
    hraw[3] = *(const float4*)(hp + 36);
  }

#pragma unroll
  for (int n = 0; n < 4; ++n) {
    const unsigned short* bp = wsW3 + (size_t)(n * 16 + r16) * 128 + kg * 8;
    f32x4 q0 = (f32x4)(0.0f);
#pragma unroll
    for (int f = 0; f < 4; ++f) {
      bf16x8 bb = *(const bf16x8*)(bp + f * 32);
      q0 = MFMA(bb, a0[f], q0, 0, 0, 0);
    }
    const f32x4 b4 = *(const f32x4*)(b3 + n * 16 + kg * 4);
    u16x4 xo;
#pragma unroll
    for (int q = 0; q < 4; ++q) xo[q] = f2b(fmaxf(q0[q] + b4[q], 0.0f));
    *(u16x4*)(xls + (wbase + r16) * XSTR + n * 16 + kg * 4) = xo;
  }
  {
    float4* wd = (float4*)wlds;
#pragma unroll
    for (int r = 0; r < 6; ++r) wd[r * NTG + tid] = wst[r];
  }
  __syncthreads();

#pragma unroll 1
  for (int c = 0; c < 4; ++c) {
    const int co = c * 64;
    const float* bcp = wsB + c * 256;
    bf16x8 ax0, ax1, ah0, ah1;
    {
      const unsigned short* xp = xls + (wbase + r16) * XSTR + kg * 8;
      ax0 = *(const bf16x8*)(xp);
      ax1 = *(const bf16x8*)(xp + 32);
    }
    ah0 = cvt8(make_float4(hraw[0].x, hraw[0].y, hraw[0].z, hraw[0].w),
               make_float4(hraw[1].x, hraw[1].y, hraw[1].z, hraw[1].w));
    ah1 = cvt8(make_float4(hraw[2].x, hraw[2].y, hraw[2].z, hraw[2].w),
               make_float4(hraw[3].x, hraw[3].y, hraw[3].z, hraw[3].w));
    if (c < 3) {
      const float* hp = memF + (size_t)(m_base + r16) * 256 + (c + 1) * 64 + kg * 8;
      hraw[0] = *(const float4*)(hp);
      hraw[1] = *(const float4*)(hp + 4);
      hraw[2] = *(const float4*)(hp + 32);
      hraw[3] = *(const float4*)(hp + 36);
    }
    const unsigned short* wl = wlds + lane * 8;
#pragma unroll 1
    for (int jt = 0; jt < 4; ++jt) {
      const unsigned short* wjt = wl + jt * 6144;
      bf16x8 xr0 = *(const bf16x8*)(wjt);
      bf16x8 xr1 = *(const bf16x8*)(wjt + 512);
      bf16x8 hr0 = *(const bf16x8*)(wjt + 1024);
      bf16x8 hr1 = *(const bf16x8*)(wjt + 1536);
      bf16x8 xz0 = *(const bf16x8*)(wjt + 2048);
      bf16x8 xz1 = *(const bf16x8*)(wjt + 2560);
      bf16x8 hz0 = *(const bf16x8*)(wjt + 3072);
      bf16x8 hz1 = *(const bf16x8*)(wjt + 3584);
      bf16x8 xn0 = *(const bf16x8*)(wjt + 4096);
      bf16x8 xn1 = *(const bf16x8*)(wjt + 4608);
      bf16x8 hn0 = *(const bf16x8*)(wjt + 5120);
      bf16x8 hn1 = *(const bf16x8*)(wjt + 5632);
      f32x4 sr = (f32x4)(0.0f), sz = (f32x4)(0.0f), sn = (f32x4)(0.0f), tn = (f32x4)(0.0f);
      sr = MFMA(xr0, ax0, sr, 0, 0, 0);
      sr = MFMA(xr1, ax1, sr, 0, 0, 0);
      sr = MFMA(hr0, ah0, sr, 0, 0, 0);
      sr = MFMA(hr1, ah1, sr, 0, 0, 0);
      sz = MFMA(xz0, ax0, sz, 0, 0, 0);
      sz = MFMA(xz1, ax1, sz, 0, 0, 0);
      sz = MFMA(hz0, ah0, sz, 0, 0, 0);
      sz = MFMA(hz1, ah1, sz, 0, 0, 0);
      sn = MFMA(xn0, ax0, sn, 0, 0, 0);
      sn = MFMA(xn1, ax1, sn, 0, 0, 0);
      tn = MFMA(hn0, ah0, tn, 0, 0, 0);
      tn = MFMA(hn1, ah1, tn, 0, 0, 0);
      const int jb = jt * 16 + kg * 4;
      const f32x4 ho4 = *(const f32x4*)(memF + (size_t)(m_base + r16) * 256 + co + jb);
      const f32x4 rb4 = *(const f32x4*)(bcp + jb);
      const f32x4 zb4 = *(const f32x4*)(bcp + 64 + jb);
      const f32x4 ib4 = *(const f32x4*)(bcp + 128 + jb);
      const f32x4 hb4 = *(const f32x4*)(bcp + 192 + jb);
      f32x4 nhv;
      u16x4 xo;
#pragma unroll
      for (int q = 0; q < 4; ++q) {
        const float rg = sigmoidf_(sr[q] + rb4[q]);
        const float zg = sigmoidf_(sz[q] + zb4[q]);
        const float ng = tanhf_((sn[q] + ib4[q]) + rg * (tn[q] + hb4[q]));
        const float nh = (1.0f - zg) * ng + zg * ho4[q];
        nhv[q] = nh;
        xo[q] = f2b(nh);
      }
      *(f32x4*)(outMem + (size_t)(m_base + r16) * 256 + co + jb) = nhv;
      *(u16x4*)(xls + (wbase + r16) * XSTR + jb) = xo;
    }
    if (c < 3) {
      __syncthreads();
      const float4* wsrc = (const float4*)(wsW + (size_t)(c + 1) * 24576);
      float4* wd = (float4*)wlds;
#pragma unroll
      for (int r = 0; r < 6; ++r) wd[r * NTG + tid] = wsrc[r * NTG + tid];
      __syncthreads();
    }
  }

  // ---- heads ----
  bf16x8 ex0, ex1;
  {
    const unsigned short* xp = xls + (wbase + r16) * XSTR + kg * 8;
    ex0 = *(const bf16x8*)(xp);
    ex1 = *(const bf16x8*)(xp + 32);
  }
  f32x4 ha[8];
#pragma unroll
  for (int n = 0; n < 8; ++n) ha[n] = (f32x4)(0.0f);
#pragma unroll
  for (int n = 0; n < 8; ++n) {
    const unsigned short* wp = wsH + (size_t)(n * 16 + r16) * 64 + kg * 8;
    bf16x8 b0 = *(const bf16x8*)(wp);
    bf16x8 b1 = *(const bf16x8*)(wp + 32);
    ha[n] = MFMA(b0, ex0, ha[n], 0, 0, 0);
    ha[n] = MFMA(b1, ex1, ha[n], 0, 0, 0);
  }
  float l0 = 0.0f, l1 = 0.0f, l2 = 0.0f, vv = 0.0f;
  const int jb0 = kg * 4;
#pragma unroll
  for (int t = 0; t < 4; ++t) {
    const f32x4 ba4 = *(const f32x4*)(ab1 + t * 16 + jb0);
    const f32x4 w0 = *(const f32x4*)(aw2 + t * 16 + jb0);
    const f32x4 w1v = *(const f32x4*)(aw2 + 64 + t * 16 + jb0);
    const f32x4 w2v = *(const f32x4*)(aw2 + 128 + t * 16 + jb0);
    const f32x4 bc4 = *(const f32x4*)(cb1 + t * 16 + jb0);
    const f32x4 wc4 = *(const f32x4*)(cw2 + t * 16 + jb0);
#pragma unroll
    for (int q = 0; q < 4; ++q) {
      const float av = fmaxf(ha[t][q] + ba4[q], 0.0f);
      const float cv = fmaxf(ha[t + 4][q] + bc4[q], 0.0f);
      l0 += av * w0[q]; l1 += av * w1v[q]; l2 += av * w2v[q];
      vv += cv * wc4[q];
    }
  }
  l0 += __shfl_xor(l0, 16); l0 += __shfl_xor(l0, 32);
  l1 += __shfl_xor(l1, 16); l1 += __shfl_xor(l1, 32);
  l2 += __shfl_xor(l2, 16); l2 += __shfl_xor(l2, 32);
  vv += __shfl_xor(vv, 16); vv += __shfl_xor(vv, 32);
  if (kg == 0) {
    const int sq = m_base + r16;
    const float g0 = l0 + ab2[0], g1 = l1 + ab2[1], g2 = l2 + ab2[2];
    const float mx = fmaxf(g0, fmaxf(g1, g2));
    const float lse = mx + __logf(__expf(g0 - mx) + __expf(g1 - mx) + __expf(g2 - mx));
    out[(size_t)sq * 3 + 0] = g0 - lse;
    out[(size_t)sq * 3 + 1] = g1 - lse;
    out[(size_t)sq * 3 + 2] = g2 - lse;
    out[(size_t)3 * BATCH + sq] = vv + cb2[0];
  }
}

extern "C" void kernel_launch(void* const* d_in, const int* in_sizes, int n_in,
                              void* d_out, int out_size, void* d_ws, size_t ws_size,
                              hipStream_t stream) {
  (void)in_sizes; (void)n_in; (void)out_size; (void)ws_size;
  const float* obs = (const float*)d_in[0];
  const float* mem = (const float*)d_in[1];
  const float* w1 = (const float*)d_in[2];
  const float* b1 = (const float*)d_in[3];
  const float* w2 = (const float*)d_in[4];
  const float* b2 = (const float*)d_in[5];
  const float* w3 = (const float*)d_in[6];
  const float* b3 = (const float*)d_in[7];
  const float* gw[16];
  for (int i = 0; i < 16; ++i) gw[i] = (const float*)d_in[8 + i];
  const float* aw1 = (const float*)d_in[24];
  const float* ab1 = (const float*)d_in[25];
  const float* aw2 = (const float*)d_in[26];
  const float* ab2 = (const float*)d_in[27];
  const float* cw1 = (const float*)d_in[28];
  const float* cb1 = (const float*)d_in[29];
  const float* cw2 = (const float*)d_in[30];
  const float* cb2 = (const float*)d_in[31];

  float* out = (float*)d_out;

  unsigned short* c2b = (unsigned short*)d_ws;                 // 128*B u16
  unsigned short* wsW = c2b + (size_t)128 * BATCH;             // 4*24576
  unsigned short* wsH = wsW + 98304;                           // 8192
  unsigned short* wsW3 = wsH + 8192;                           // 8192
  float* wsB = (float*)(wsW3 + 8192);                          // 1024 f32

  hipLaunchKernelGGL(k_front, dim3(1024 + 720), dim3(NT), 0, stream,
                     obs, w1, b1, w2, b2, c2b,
                     gw[0], gw[1], gw[4], gw[5], gw[8], gw[9], gw[12], gw[13],
                     gw[2], gw[6], gw[10], gw[14],
                     gw[3], gw[7], gw[11], gw[15],
                     aw1, cw1, w3, wsW, wsH, wsW3, wsB);
  hipLaunchKernelGGL(k_gru, dim3(BATCH / 128), dim3(NTG), 0, stream,
                     c2b, mem, wsW, wsW3, wsB, wsH, b3,
                     ab1, cb1, aw2, ab2, cw2, cb2, out);
}

// Round 19
// 101.232 us; speedup vs baseline: 1.2667x; 1.0627x over previous
//
#include <hip/hip_runtime.h>

#define BATCH 65536
#define NT 256
#define MFMA __builtin_amdgcn_mfma_f32_16x16x32_bf16

typedef short bf16x8 __attribute__((ext_vector_type(8)));
typedef float f32x4 __attribute__((ext_vector_type(4)));
typedef unsigned short u16x8 __attribute__((ext_vector_type(8)));
typedef unsigned short u16x4 __attribute__((ext_vector_type(4)));

__device__ __forceinline__ float sigmoidf_(float x) { return 1.0f / (1.0f + __expf(-x)); }
__device__ __forceinline__ float tanhf_(float x) { return 2.0f / (1.0f + __expf(-2.0f * x)) - 1.0f; }
__device__ __forceinline__ unsigned short f2b(float f) {
  union { float f; unsigned int u; } v; v.f = f;
  unsigned int r = (v.u + 0x7FFFu + ((v.u >> 16) & 1u)) >> 16;
  return (unsigned short)r;
}
__device__ __forceinline__ float b2f(unsigned short u) {
  return __uint_as_float(((unsigned int)u) << 16);
}
__device__ __forceinline__ bf16x8 cvt8(float4 a, float4 b) {
  union { unsigned short u[8]; bf16x8 v; } t;
  t.u[0] = f2b(a.x); t.u[1] = f2b(a.y); t.u[2] = f2b(a.z); t.u[3] = f2b(a.w);
  t.u[4] = f2b(b.x); t.u[5] = f2b(b.y); t.u[6] = f2b(b.z); t.u[7] = f2b(b.w);
  return t.v;
}

// ---------------- k_front: conv1+conv2 (blocks 0..1023, bf16 obs LDS)
//                  + prep (blocks 1024..1743)  [R15 proven, unchanged] ----------------
#define OSTR 149
#define PSTR 146
__global__ __launch_bounds__(NT) void k_front(
    const float* __restrict__ obs, const float* __restrict__ w1,
    const float* __restrict__ b1, const float* __restrict__ w2,
    const float* __restrict__ b2, unsigned short* __restrict__ c2b,
    const float* __restrict__ W0, const float* __restrict__ W1,
    const float* __restrict__ W2, const float* __restrict__ W3,
    const float* __restrict__ W4, const float* __restrict__ W5,
    const float* __restrict__ W6, const float* __restrict__ W7,
    const float* __restrict__ bi0, const float* __restrict__ bi1,
    const float* __restrict__ bi2, const float* __restrict__ bi3,
    const float* __restrict__ bh0, const float* __restrict__ bh1,
    const float* __restrict__ bh2, const float* __restrict__ bh3,
    const float* __restrict__ aw1, const float* __restrict__ cw1,
    const float* __restrict__ w3s,
    unsigned short* __restrict__ wsW, unsigned short* __restrict__ wsH,
    unsigned short* __restrict__ wsW3, float* __restrict__ wsB) {
  const int tid = threadIdx.x;
  const int b = blockIdx.x;

  if (b >= 1024) {
    const int pb = b - 1024;
    const int y = pb / 48;
    const int i = (pb % 48) * NT + tid;
    if (y < 8) {
      if (i >= 12288) return;
      const float* src = (y == 0) ? W0 : (y == 1) ? W1 : (y == 2) ? W2 : (y == 3) ? W3
                       : (y == 4) ? W4 : (y == 5) ? W5 : (y == 6) ? W6 : W7;
      const int c = y >> 1, p = y & 1;
      const int j = i >> 6, k = i & 63;
      const int g = j >> 6, jrow = j & 63;
      const int jt = jrow >> 4, r16i = jrow & 15;
      const int kseg = k >> 5, kgv = (k & 31) >> 3, e = k & 7;
      const int lane = kgv * 16 + r16i;
      const int q = g * 4 + p * 2 + kseg;
      wsW[c * 24576 + ((jt * 12 + q) * 64 + lane) * 8 + e] = f2b(src[i]);
    } else if (y == 8) {
      if (i < 4096) wsH[i] = f2b(aw1[i]);
    } else if (y == 9) {
      if (i < 4096) wsH[4096 + i] = f2b(cw1[i]);
    } else if (y == 10) {
      if (i < 8192) wsW3[i] = f2b(w3s[i]);
    } else {
      const int c = y - 11;
      if (i < 256) {
        const float* bi = (c == 0) ? bi0 : (c == 1) ? bi1 : (c == 2) ? bi2 : bi3;
        const float* bh = (c == 0) ? bh0 : (c == 1) ? bh1 : (c == 2) ? bh2 : bh3;
        const int j = i & 63, g = i >> 6;
        float v = (g == 0) ? bi[j] + bh[j]
                : (g == 1) ? bi[64 + j] + bh[64 + j]
                : (g == 2) ? bi[128 + j] : bh[128 + j];
        wsB[c * 256 + i] = v;
      }
    }
    return;
  }

  __shared__ unsigned short obs_b[64 * OSTR];
  __shared__ unsigned short pooled[64 * PSTR];
  const int lane = tid & 63;
  const int wave = tid >> 6;
  const int m_base = b * 64;

  {
    const float4* src = (const float4*)(obs + (size_t)m_base * 147);
#pragma unroll 1
    for (int i = tid; i < 2352; i += NT) {
      const float4 v = src[i];
      int idx = i * 4;
      int s = idx / 147;
      int c = idx - s * 147;
      obs_b[s * OSTR + c] = f2b(v.x);
      if (++c == 147) { c = 0; ++s; } obs_b[s * OSTR + c] = f2b(v.y);
      if (++c == 147) { c = 0; ++s; } obs_b[s * OSTR + c] = f2b(v.z);
      if (++c == 147) { c = 0; ++s; } obs_b[s * OSTR + c] = f2b(v.w);
    }
  }
  __syncthreads();

  if (wave < 3) {
    const int ph = wave, s = lane;
    float r[3][21];
#pragma unroll
    for (int rr = 0; rr < 3; ++rr)
#pragma unroll
      for (int i = 0; i < 21; ++i) r[rr][i] = b2f(obs_b[s * OSTR + (2 * ph + rr) * 21 + i]);
#pragma unroll 1
    for (int oc = 0; oc < 16; ++oc) {
      float wv[12];
#pragma unroll
      for (int i = 0; i < 12; ++i) wv[i] = w1[oc * 12 + i];
      const float bias = b1[oc];
#pragma unroll
      for (int pw = 0; pw < 3; ++pw) {
        float m = 0.0f;
#pragma unroll
        for (int dh = 0; dh < 2; ++dh)
#pragma unroll
          for (int dw = 0; dw < 2; ++dw) {
            float acc = bias;
#pragma unroll
            for (int kh = 0; kh < 2; ++kh)
#pragma unroll
              for (int kw = 0; kw < 2; ++kw)
#pragma unroll
                for (int c = 0; c < 3; ++c)
                  acc += r[dh + kh][(2 * pw + dw + kw) * 3 + c] * wv[c * 4 + kh * 2 + kw];
            m = fmaxf(m, fmaxf(acc, 0.0f));
          }
        pooled[s * PSTR + oc * 9 + ph * 3 + pw] = f2b(m);
      }
    }
  }
  __syncthreads();

  {
    const int g = wave, s = lane;
    const int ocb = g * 8;
    float acc[8][4];
#pragma unroll
    for (int u = 0; u < 8; ++u) {
      const float bb = b2[ocb + u];
      acc[u][0] = bb; acc[u][1] = bb; acc[u][2] = bb; acc[u][3] = bb;
    }
#pragma unroll 1
    for (int ic = 0; ic < 16; ++ic) {
      float p9[9];
#pragma unroll
      for (int p = 0; p < 9; ++p) p9[p] = b2f(pooled[s * PSTR + ic * 9 + p]);
#pragma unroll
      for (int u = 0; u < 8; ++u) {
        float w[4];
#pragma unroll
        for (int i = 0; i < 4; ++i) w[i] = w2[((ocb + u) * 16 + ic) * 4 + i];
#pragma unroll
        for (int oh = 0; oh < 2; ++oh)
#pragma unroll
          for (int ow = 0; ow < 2; ++ow)
            acc[u][oh * 2 + ow] += p9[(oh + 0) * 3 + (ow + 0)] * w[0] +
                                   p9[(oh + 0) * 3 + (ow + 1)] * w[1] +
                                   p9[(oh + 1) * 3 + (ow + 0)] * w[2] +
                                   p9[(oh + 1) * 3 + (ow + 1)] * w[3];
      }
    }
    unsigned short ob[32];
#pragma unroll
    for (int u = 0; u < 8; ++u)
#pragma unroll
      for (int p = 0; p < 4; ++p) ob[u * 4 + p] = f2b(fmaxf(acc[u][p], 0.0f));
#pragma unroll
    for (int i = 0; i < 4; ++i)
      *(u16x8*)(c2b + (size_t)(m_base + s) * 128 + g * 32 + 8 * i) = *(const u16x8*)(ob + 8 * i);
  }
}

// ---------------- fused: conv3-GEMM + 4 GRU cells + heads ----------------
// M=32/wave quadrant: NT=256 (4 waves), each wave owns 2 M-tiles (32 samples),
// 128 samples/block, grid 512. LDS weights (R7 fragment order) + swapped
// operands (R13). 12 ds_reads/jt now serve 32 samples (2x amortization);
// waves/SIMD drops 4->2. Synchronous barrier-pair weight copies only
// (R8/R16/R17: reg-state across barriers spills).
#define XSTR 88
__global__ __launch_bounds__(NT, 2) void k_gru(
    const unsigned short* __restrict__ c2b,
    const float* __restrict__ memF,
    const unsigned short* __restrict__ wsW,
    const unsigned short* __restrict__ wsW3,
    const float* __restrict__ wsB,
    const unsigned short* __restrict__ wsH,
    const float* __restrict__ b3,
    const float* __restrict__ ab1, const float* __restrict__ cb1,
    const float* __restrict__ aw2, const float* __restrict__ ab2,
    const float* __restrict__ cw2, const float* __restrict__ cb2,
    float* __restrict__ out) {
  __shared__ unsigned short wlds[24576];      // 48KB
  __shared__ unsigned short xls[128 * XSTR];  // 22.5KB; total 70.5KB -> 2 blocks/CU
  const int tid = threadIdx.x;
  const int lane = tid & 63;
  const int wave = tid >> 6;            // 0..3
  const int r16 = lane & 15;
  const int kg = lane >> 4;
  const int wbase = wave * 32;          // 32 samples per wave
  const int m_base = blockIdx.x * 128 + wbase;
  float* outMem = out + (size_t)4 * BATCH;

  // ---- prologue: cell-0 weight loads (12 float4/thread, reg-staged over stage0) ----
  float4 wst[12];
  {
    const float4* wsrc = (const float4*)wsW;
#pragma unroll
    for (int r = 0; r < 12; ++r) wst[r] = wsrc[r * NT + tid];
  }
  bf16x8 a0[2][4];
  float4 hraw[2][4];
#pragma unroll
  for (int Mt = 0; Mt < 2; ++Mt) {
    const unsigned short* ap = c2b + (size_t)(m_base + Mt * 16 + r16) * 128 + kg * 8;
#pragma unroll
    for (int f = 0; f < 4; ++f) a0[Mt][f] = *(const bf16x8*)(ap + f * 32);
    const float* hp = memF + (size_t)(m_base + Mt * 16 + r16) * 256 + kg * 8;
    hraw[Mt][0] = *(const float4*)(hp);
    hraw[Mt][1] = *(const float4*)(hp + 4);
    hraw[Mt][2] = *(const float4*)(hp + 32);
    hraw[Mt][3] = *(const float4*)(hp + 36);
  }

  // ---- stage 0: x = relu(c2 @ w3^T + b3), D[oc][sample], 2 M-tiles ----
#pragma unroll
  for (int n = 0; n < 4; ++n) {
    const unsigned short* bp = wsW3 + (size_t)(n * 16 + r16) * 128 + kg * 8;
    bf16x8 wb[4];
#pragma unroll
    for (int f = 0; f < 4; ++f) wb[f] = *(const bf16x8*)(bp + f * 32);
    const f32x4 b4 = *(const f32x4*)(b3 + n * 16 + kg * 4);
#pragma unroll
    for (int Mt = 0; Mt < 2; ++Mt) {
      f32x4 q0 = (f32x4)(0.0f);
#pragma unroll
      for (int f = 0; f < 4; ++f) q0 = MFMA(wb[f], a0[Mt][f], q0, 0, 0, 0);
      u16x4 xo;
#pragma unroll
      for (int q = 0; q < 4; ++q) xo[q] = f2b(fmaxf(q0[q] + b4[q], 0.0f));
      *(u16x4*)(xls + (wbase + Mt * 16 + r16) * XSTR + n * 16 + kg * 4) = xo;
    }
  }
  // publish cell-0 weights
  {
    float4* wd = (float4*)wlds;
#pragma unroll
    for (int r = 0; r < 12; ++r) wd[r * NT + tid] = wst[r];
  }
  __syncthreads();

  // ---- 4 GRU cells ----
#pragma unroll 1
  for (int c = 0; c < 4; ++c) {
    const int co = c * 64;
    const float* bcp = wsB + c * 256;
    bf16x8 ax[2][2], ah[2][2];
#pragma unroll
    for (int Mt = 0; Mt < 2; ++Mt) {
      const unsigned short* xp = xls + (wbase + Mt * 16 + r16) * XSTR + kg * 8;
      ax[Mt][0] = *(const bf16x8*)(xp);
      ax[Mt][1] = *(const bf16x8*)(xp + 32);
      ah[Mt][0] = cvt8(make_float4(hraw[Mt][0].x, hraw[Mt][0].y, hraw[Mt][0].z, hraw[Mt][0].w),
                       make_float4(hraw[Mt][1].x, hraw[Mt][1].y, hraw[Mt][1].z, hraw[Mt][1].w));
      ah[Mt][1] = cvt8(make_float4(hraw[Mt][2].x, hraw[Mt][2].y, hraw[Mt][2].z, hraw[Mt][2].w),
                       make_float4(hraw[Mt][3].x, hraw[Mt][3].y, hraw[Mt][3].z, hraw[Mt][3].w));
    }
    if (c < 3) {
#pragma unroll
      for (int Mt = 0; Mt < 2; ++Mt) {
        const float* hp = memF + (size_t)(m_base + Mt * 16 + r16) * 256 + (c + 1) * 64 + kg * 8;
        hraw[Mt][0] = *(const float4*)(hp);
        hraw[Mt][1] = *(const float4*)(hp + 4);
        hraw[Mt][2] = *(const float4*)(hp + 32);
        hraw[Mt][3] = *(const float4*)(hp + 36);
      }
    }
    const unsigned short* wl = wlds + lane * 8;
#pragma unroll 1
    for (int jt = 0; jt < 4; ++jt) {
      const unsigned short* wjt = wl + jt * 6144;
      bf16x8 xr0 = *(const bf16x8*)(wjt);
      bf16x8 xr1 = *(const bf16x8*)(wjt + 512);
      bf16x8 hr0 = *(const bf16x8*)(wjt + 1024);
      bf16x8 hr1 = *(const bf16x8*)(wjt + 1536);
      bf16x8 xz0 = *(const bf16x8*)(wjt + 2048);
      bf16x8 xz1 = *(const bf16x8*)(wjt + 2560);
      bf16x8 hz0 = *(const bf16x8*)(wjt + 3072);
      bf16x8 hz1 = *(const bf16x8*)(wjt + 3584);
      bf16x8 xn0 = *(const bf16x8*)(wjt + 4096);
      bf16x8 xn1 = *(const bf16x8*)(wjt + 4608);
      bf16x8 hn0 = *(const bf16x8*)(wjt + 5120);
      bf16x8 hn1 = *(const bf16x8*)(wjt + 5632);
      f32x4 sr[2], sz[2], sn[2], tn[2];
#pragma unroll
      for (int Mt = 0; Mt < 2; ++Mt) {
        sr[Mt] = (f32x4)(0.0f); sz[Mt] = (f32x4)(0.0f);
        sn[Mt] = (f32x4)(0.0f); tn[Mt] = (f32x4)(0.0f);
      }
#pragma unroll
      for (int Mt = 0; Mt < 2; ++Mt) {
        sr[Mt] = MFMA(xr0, ax[Mt][0], sr[Mt], 0, 0, 0);
        sr[Mt] = MFMA(xr1, ax[Mt][1], sr[Mt], 0, 0, 0);
        sr[Mt] = MFMA(hr0, ah[Mt][0], sr[Mt], 0, 0, 0);
        sr[Mt] = MFMA(hr1, ah[Mt][1], sr[Mt], 0, 0, 0);
        sz[Mt] = MFMA(xz0, ax[Mt][0], sz[Mt], 0, 0, 0);
        sz[Mt] = MFMA(xz1, ax[Mt][1], sz[Mt], 0, 0, 0);
        sz[Mt] = MFMA(hz0, ah[Mt][0], sz[Mt], 0, 0, 0);
        sz[Mt] = MFMA(hz1, ah[Mt][1], sz[Mt], 0, 0, 0);
        sn[Mt] = MFMA(xn0, ax[Mt][0], sn[Mt], 0, 0, 0);
        sn[Mt] = MFMA(xn1, ax[Mt][1], sn[Mt], 0, 0, 0);
        tn[Mt] = MFMA(hn0, ah[Mt][0], tn[Mt], 0, 0, 0);
        tn[Mt] = MFMA(hn1, ah[Mt][1], tn[Mt], 0, 0, 0);
      }
      const int jb = jt * 16 + kg * 4;
      const f32x4 rb4 = *(const f32x4*)(bcp + jb);
      const f32x4 zb4 = *(const f32x4*)(bcp + 64 + jb);
      const f32x4 ib4 = *(const f32x4*)(bcp + 128 + jb);
      const f32x4 hb4 = *(const f32x4*)(bcp + 192 + jb);
#pragma unroll
      for (int Mt = 0; Mt < 2; ++Mt) {
        const f32x4 ho4 = *(const f32x4*)(memF + (size_t)(m_base + Mt * 16 + r16) * 256 + co + jb);
        f32x4 nhv;
        u16x4 xo;
#pragma unroll
        for (int q = 0; q < 4; ++q) {
          const float rg = sigmoidf_(sr[Mt][q] + rb4[q]);
          const float zg = sigmoidf_(sz[Mt][q] + zb4[q]);
          const float ng = tanhf_((sn[Mt][q] + ib4[q]) + rg * (tn[Mt][q] + hb4[q]));
          const float nh = (1.0f - zg) * ng + zg * ho4[q];
          nhv[q] = nh;
          xo[q] = f2b(nh);
        }
        *(f32x4*)(outMem + (size_t)(m_base + Mt * 16 + r16) * 256 + co + jb) = nhv;
        *(u16x4*)(xls + (wbase + Mt * 16 + r16) * XSTR + jb) = xo;
      }
    }
    if (c < 3) {
      __syncthreads();
      const float4* wsrc = (const float4*)(wsW + (size_t)(c + 1) * 24576);
      float4* wd = (float4*)wlds;
#pragma unroll
      for (int r = 0; r < 12; ++r) wd[r * NT + tid] = wsrc[r * NT + tid];
      __syncthreads();
    }
  }

  // ---- heads: per M-tile ----
  bf16x8 ex[2][2];
#pragma unroll
  for (int Mt = 0; Mt < 2; ++Mt) {
    const unsigned short* xp = xls + (wbase + Mt * 16 + r16) * XSTR + kg * 8;
    ex[Mt][0] = *(const bf16x8*)(xp);
    ex[Mt][1] = *(const bf16x8*)(xp + 32);
  }
  f32x4 ha[2][8];
#pragma unroll
  for (int Mt = 0; Mt < 2; ++Mt)
#pragma unroll
    for (int n = 0; n < 8; ++n) ha[Mt][n] = (f32x4)(0.0f);
#pragma unroll
  for (int n = 0; n < 8; ++n) {
    const unsigned short* wp = wsH + (size_t)(n * 16 + r16) * 64 + kg * 8;
    bf16x8 b0 = *(const bf16x8*)(wp);
    bf16x8 b1 = *(const bf16x8*)(wp + 32);
#pragma unroll
    for (int Mt = 0; Mt < 2; ++Mt) {
      ha[Mt][n] = MFMA(b0, ex[Mt][0], ha[Mt][n], 0, 0, 0);
      ha[Mt][n] = MFMA(b1, ex[Mt][1], ha[Mt][n], 0, 0, 0);
    }
  }
  const int jb0 = kg * 4;
  float l0[2] = {0.0f, 0.0f}, l1[2] = {0.0f, 0.0f}, l2[2] = {0.0f, 0.0f}, vv[2] = {0.0f, 0.0f};
#pragma unroll
  for (int t = 0; t < 4; ++t) {
    const f32x4 ba4 = *(const f32x4*)(ab1 + t * 16 + jb0);
    const f32x4 w0 = *(const f32x4*)(aw2 + t * 16 + jb0);
    const f32x4 w1v = *(const f32x4*)(aw2 + 64 + t * 16 + jb0);
    const f32x4 w2v = *(const f32x4*)(aw2 + 128 + t * 16 + jb0);
    const f32x4 bc4 = *(const f32x4*)(cb1 + t * 16 + jb0);
    const f32x4 wc4 = *(const f32x4*)(cw2 + t * 16 + jb0);
#pragma unroll
    for (int Mt = 0; Mt < 2; ++Mt)
#pragma unroll
      for (int q = 0; q < 4; ++q) {
        const float av = fmaxf(ha[Mt][t][q] + ba4[q], 0.0f);
        const float cv = fmaxf(ha[Mt][t + 4][q] + bc4[q], 0.0f);
        l0[Mt] += av * w0[q]; l1[Mt] += av * w1v[q]; l2[Mt] += av * w2v[q];
        vv[Mt] += cv * wc4[q];
      }
  }
#pragma unroll
  for (int Mt = 0; Mt < 2; ++Mt) {
    l0[Mt] += __shfl_xor(l0[Mt], 16); l0[Mt] += __shfl_xor(l0[Mt], 32);
    l1[Mt] += __shfl_xor(l1[Mt], 16); l1[Mt] += __shfl_xor(l1[Mt], 32);
    l2[Mt] += __shfl_xor(l2[Mt], 16); l2[Mt] += __shfl_xor(l2[Mt], 32);
    vv[Mt] += __shfl_xor(vv[Mt], 16); vv[Mt] += __shfl_xor(vv[Mt], 32);
    if (kg == 0) {
      const int sq = m_base + Mt * 16 + r16;
      const float g0 = l0[Mt] + ab2[0], g1 = l1[Mt] + ab2[1], g2 = l2[Mt] + ab2[2];
      const float mx = fmaxf(g0, fmaxf(g1, g2));
      const float lse = mx + __logf(__expf(g0 - mx) + __expf(g1 - mx) + __expf(g2 - mx));
      out[(size_t)sq * 3 + 0] = g0 - lse;
      out[(size_t)sq * 3 + 1] = g1 - lse;
      out[(size_t)sq * 3 + 2] = g2 - lse;
      out[(size_t)3 * BATCH + sq] = vv[Mt] + cb2[0];
    }
  }
}

extern "C" void kernel_launch(void* const* d_in, const int* in_sizes, int n_in,
                              void* d_out, int out_size, void* d_ws, size_t ws_size,
                              hipStream_t stream) {
  (void)in_sizes; (void)n_in; (void)out_size; (void)ws_size;
  const float* obs = (const float*)d_in[0];
  const float* mem = (const float*)d_in[1];
  const float* w1 = (const float*)d_in[2];
  const float* b1 = (const float*)d_in[3];
  const float* w2 = (const float*)d_in[4];
  const float* b2 = (const float*)d_in[5];
  const float* w3 = (const float*)d_in[6];
  const float* b3 = (const float*)d_in[7];
  const float* gw[16];
  for (int i = 0; i < 16; ++i) gw[i] = (const float*)d_in[8 + i];
  const float* aw1 = (const float*)d_in[24];
  const float* ab1 = (const float*)d_in[25];
  const float* aw2 = (const float*)d_in[26];
  const float* ab2 = (const float*)d_in[27];
  const float* cw1 = (const float*)d_in[28];
  const float* cb1 = (const float*)d_in[29];
  const float* cw2 = (const float*)d_in[30];
  const float* cb2 = (const float*)d_in[31];

  float* out = (float*)d_out;

  unsigned short* c2b = (unsigned short*)d_ws;                 // 128*B u16
  unsigned short* wsW = c2b + (size_t)128 * BATCH;             // 4*24576
  unsigned short* wsH = wsW + 98304;                           // 8192
  unsigned short* wsW3 = wsH + 8192;                           // 8192
  float* wsB = (float*)(wsW3 + 8192);                          // 1024 f32

  hipLaunchKernelGGL(k_front, dim3(1024 + 720), dim3(NT), 0, stream,
                     obs, w1, b1, w2, b2, c2b,
                     gw[0], gw[1], gw[4], gw[5], gw[8], gw[9], gw[12], gw[13],
                     gw[2], gw[6], gw[10], gw[14],
                     gw[3], gw[7], gw[11], gw[15],
                     aw1, cw1, w3, wsW, wsH, wsW3, wsB);
  hipLaunchKernelGGL(k_gru, dim3(BATCH / 128), dim3(NT), 0, stream,
                     c2b, mem, wsW, wsW3, wsB, wsH, b3,
                     ab1, cb1, aw2, ab2, cw2, cb2, out);
}

// Round 20
// 101.219 us; speedup vs baseline: 1.2669x; 1.0001x over previous
//
#include <hip/hip_runtime.h>

#define BATCH 65536
#define NT 256
#define MFMA __builtin_amdgcn_mfma_f32_16x16x32_bf16

typedef short bf16x8 __attribute__((ext_vector_type(8)));
typedef float f32x4 __attribute__((ext_vector_type(4)));
typedef unsigned short u16x8 __attribute__((ext_vector_type(8)));
typedef unsigned short u16x4 __attribute__((ext_vector_type(4)));

__device__ __forceinline__ float sigmoidf_(float x) { return 1.0f / (1.0f + __expf(-x)); }
__device__ __forceinline__ float tanhf_(float x) { return 2.0f / (1.0f + __expf(-2.0f * x)) - 1.0f; }
__device__ __forceinline__ unsigned short f2b(float f) {
  union { float f; unsigned int u; } v; v.f = f;
  unsigned int r = (v.u + 0x7FFFu + ((v.u >> 16) & 1u)) >> 16;
  return (unsigned short)r;
}
__device__ __forceinline__ float b2f(unsigned short u) {
  return __uint_as_float(((unsigned int)u) << 16);
}
__device__ __forceinline__ bf16x8 cvt8(float4 a, float4 b) {
  union { unsigned short u[8]; bf16x8 v; } t;
  t.u[0] = f2b(a.x); t.u[1] = f2b(a.y); t.u[2] = f2b(a.z); t.u[3] = f2b(a.w);
  t.u[4] = f2b(b.x); t.u[5] = f2b(b.y); t.u[6] = f2b(b.z); t.u[7] = f2b(b.w);
  return t.v;
}

// ---------------- k_front: conv1+conv2 (blocks 0..1023, bf16 obs LDS)
//                  + prep (blocks 1024..1743)  [R15 proven, unchanged] ----------------
#define OSTR 149
#define PSTR 146
__global__ __launch_bounds__(NT) void k_front(
    const float* __restrict__ obs, const float* __restrict__ w1,
    const float* __restrict__ b1, const float* __restrict__ w2,
    const float* __restrict__ b2, unsigned short* __restrict__ c2b,
    const float* __restrict__ W0, const float* __restrict__ W1,
    const float* __restrict__ W2, const float* __restrict__ W3,
    const float* __restrict__ W4, const float* __restrict__ W5,
    const float* __restrict__ W6, const float* __restrict__ W7,
    const float* __restrict__ bi0, const float* __restrict__ bi1,
    const float* __restrict__ bi2, const float* __restrict__ bi3,
    const float* __restrict__ bh0, const float* __restrict__ bh1,
    const float* __restrict__ bh2, const float* __restrict__ bh3,
    const float* __restrict__ aw1, const float* __restrict__ cw1,
    const float* __restrict__ w3s,
    unsigned short* __restrict__ wsW, unsigned short* __restrict__ wsH,
    unsigned short* __restrict__ wsW3, float* __restrict__ wsB) {
  const int tid = threadIdx.x;
  const int b = blockIdx.x;

  if (b >= 1024) {
    const int pb = b - 1024;
    const int y = pb / 48;
    const int i = (pb % 48) * NT + tid;
    if (y < 8) {
      if (i >= 12288) return;
      const float* src = (y == 0) ? W0 : (y == 1) ? W1 : (y == 2) ? W2 : (y == 3) ? W3
                       : (y == 4) ? W4 : (y == 5) ? W5 : (y == 6) ? W6 : W7;
      const int c = y >> 1, p = y & 1;
      const int j = i >> 6, k = i & 63;
      const int g = j >> 6, jrow = j & 63;
      const int jt = jrow >> 4, r16i = jrow & 15;
      const int kseg = k >> 5, kgv = (k & 31) >> 3, e = k & 7;
      const int lane = kgv * 16 + r16i;
      const int q = g * 4 + p * 2 + kseg;
      wsW[c * 24576 + ((jt * 12 + q) * 64 + lane) * 8 + e] = f2b(src[i]);
    } else if (y == 8) {
      if (i < 4096) wsH[i] = f2b(aw1[i]);
    } else if (y == 9) {
      if (i < 4096) wsH[4096 + i] = f2b(cw1[i]);
    } else if (y == 10) {
      if (i < 8192) wsW3[i] = f2b(w3s[i]);
    } else {
      const int c = y - 11;
      if (i < 256) {
        const float* bi = (c == 0) ? bi0 : (c == 1) ? bi1 : (c == 2) ? bi2 : bi3;
        const float* bh = (c == 0) ? bh0 : (c == 1) ? bh1 : (c == 2) ? bh2 : bh3;
        const int j = i & 63, g = i >> 6;
        float v = (g == 0) ? bi[j] + bh[j]
                : (g == 1) ? bi[64 + j] + bh[64 + j]
                : (g == 2) ? bi[128 + j] : bh[128 + j];
        wsB[c * 256 + i] = v;
      }
    }
    return;
  }

  __shared__ unsigned short obs_b[64 * OSTR];
  __shared__ unsigned short pooled[64 * PSTR];
  const int lane = tid & 63;
  const int wave = tid >> 6;
  const int m_base = b * 64;

  {
    const float4* src = (const float4*)(obs + (size_t)m_base * 147);
#pragma unroll 1
    for (int i = tid; i < 2352; i += NT) {
      const float4 v = src[i];
      int idx = i * 4;
      int s = idx / 147;
      int c = idx - s * 147;
      obs_b[s * OSTR + c] = f2b(v.x);
      if (++c == 147) { c = 0; ++s; } obs_b[s * OSTR + c] = f2b(v.y);
      if (++c == 147) { c = 0; ++s; } obs_b[s * OSTR + c] = f2b(v.z);
      if (++c == 147) { c = 0; ++s; } obs_b[s * OSTR + c] = f2b(v.w);
    }
  }
  __syncthreads();

  if (wave < 3) {
    const int ph = wave, s = lane;
    float r[3][21];
#pragma unroll
    for (int rr = 0; rr < 3; ++rr)
#pragma unroll
      for (int i = 0; i < 21; ++i) r[rr][i] = b2f(obs_b[s * OSTR + (2 * ph + rr) * 21 + i]);
#pragma unroll 1
    for (int oc = 0; oc < 16; ++oc) {
      float wv[12];
#pragma unroll
      for (int i = 0; i < 12; ++i) wv[i] = w1[oc * 12 + i];
      const float bias = b1[oc];
#pragma unroll
      for (int pw = 0; pw < 3; ++pw) {
        float m = 0.0f;
#pragma unroll
        for (int dh = 0; dh < 2; ++dh)
#pragma unroll
          for (int dw = 0; dw < 2; ++dw) {
            float acc = bias;
#pragma unroll
            for (int kh = 0; kh < 2; ++kh)
#pragma unroll
              for (int kw = 0; kw < 2; ++kw)
#pragma unroll
                for (int c = 0; c < 3; ++c)
                  acc += r[dh + kh][(2 * pw + dw + kw) * 3 + c] * wv[c * 4 + kh * 2 + kw];
            m = fmaxf(m, fmaxf(acc, 0.0f));
          }
        pooled[s * PSTR + oc * 9 + ph * 3 + pw] = f2b(m);
      }
    }
  }
  __syncthreads();

  {
    const int g = wave, s = lane;
    const int ocb = g * 8;
    float acc[8][4];
#pragma unroll
    for (int u = 0; u < 8; ++u) {
      const float bb = b2[ocb + u];
      acc[u][0] = bb; acc[u][1] = bb; acc[u][2] = bb; acc[u][3] = bb;
    }
#pragma unroll 1
    for (int ic = 0; ic < 16; ++ic) {
      float p9[9];
#pragma unroll
      for (int p = 0; p < 9; ++p) p9[p] = b2f(pooled[s * PSTR + ic * 9 + p]);
#pragma unroll
      for (int u = 0; u < 8; ++u) {
        float w[4];
#pragma unroll
        for (int i = 0; i < 4; ++i) w[i] = w2[((ocb + u) * 16 + ic) * 4 + i];
#pragma unroll
        for (int oh = 0; oh < 2; ++oh)
#pragma unroll
          for (int ow = 0; ow < 2; ++ow)
            acc[u][oh * 2 + ow] += p9[(oh + 0) * 3 + (ow + 0)] * w[0] +
                                   p9[(oh + 0) * 3 + (ow + 1)] * w[1] +
                                   p9[(oh + 1) * 3 + (ow + 0)] * w[2] +
                                   p9[(oh + 1) * 3 + (ow + 1)] * w[3];
      }
    }
    unsigned short ob[32];
#pragma unroll
    for (int u = 0; u < 8; ++u)
#pragma unroll
      for (int p = 0; p < 4; ++p) ob[u * 4 + p] = f2b(fmaxf(acc[u][p], 0.0f));
#pragma unroll
    for (int i = 0; i < 4; ++i)
      *(u16x8*)(c2b + (size_t)(m_base + s) * 128 + g * 32 + 8 * i) = *(const u16x8*)(ob + 8 * i);
  }
}

// ---------------- fused: conv3-GEMM + 4 GRU cells + heads ----------------
// R19 (M=32/wave, NT=256, LDS weights, swapped operands) + unroll-2 on jt:
// at 2 waves/SIMD the jt chain has minimal TLP cover, so cross-jt ILP pays
// (R5 precedent at this exact occupancy). VGPR budget 256 at min-waves=2.
#define XSTR 88
__global__ __launch_bounds__(NT, 2) void k_gru(
    const unsigned short* __restrict__ c2b,
    const float* __restrict__ memF,
    const unsigned short* __restrict__ wsW,
    const unsigned short* __restrict__ wsW3,
    const float* __restrict__ wsB,
    const unsigned short* __restrict__ wsH,
    const float* __restrict__ b3,
    const float* __restrict__ ab1, const float* __restrict__ cb1,
    const float* __restrict__ aw2, const float* __restrict__ ab2,
    const float* __restrict__ cw2, const float* __restrict__ cb2,
    float* __restrict__ out) {
  __shared__ unsigned short wlds[24576];      // 48KB
  __shared__ unsigned short xls[128 * XSTR];  // 22.5KB; total 70.5KB -> 2 blocks/CU
  const int tid = threadIdx.x;
  const int lane = tid & 63;
  const int wave = tid >> 6;            // 0..3
  const int r16 = lane & 15;
  const int kg = lane >> 4;
  const int wbase = wave * 32;          // 32 samples per wave
  const int m_base = blockIdx.x * 128 + wbase;
  float* outMem = out + (size_t)4 * BATCH;

  // ---- prologue: cell-0 weight loads (12 float4/thread, reg-staged over stage0) ----
  float4 wst[12];
  {
    const float4* wsrc = (const float4*)wsW;
#pragma unroll
    for (int r = 0; r < 12; ++r) wst[r] = wsrc[r * NT + tid];
  }
  bf16x8 a0[2][4];
  float4 hraw[2][4];
#pragma unroll
  for (int Mt = 0; Mt < 2; ++Mt) {
    const unsigned short* ap = c2b + (size_t)(m_base + Mt * 16 + r16) * 128 + kg * 8;
#pragma unroll
    for (int f = 0; f < 4; ++f) a0[Mt][f] = *(const bf16x8*)(ap + f * 32);
    const float* hp = memF + (size_t)(m_base + Mt * 16 + r16) * 256 + kg * 8;
    hraw[Mt][0] = *(const float4*)(hp);
    hraw[Mt][1] = *(const float4*)(hp + 4);
    hraw[Mt][2] = *(const float4*)(hp + 32);
    hraw[Mt][3] = *(const float4*)(hp + 36);
  }

  // ---- stage 0: x = relu(c2 @ w3^T + b3), D[oc][sample], 2 M-tiles ----
#pragma unroll
  for (int n = 0; n < 4; ++n) {
    const unsigned short* bp = wsW3 + (size_t)(n * 16 + r16) * 128 + kg * 8;
    bf16x8 wb[4];
#pragma unroll
    for (int f = 0; f < 4; ++f) wb[f] = *(const bf16x8*)(bp + f * 32);
    const f32x4 b4 = *(const f32x4*)(b3 + n * 16 + kg * 4);
#pragma unroll
    for (int Mt = 0; Mt < 2; ++Mt) {
      f32x4 q0 = (f32x4)(0.0f);
#pragma unroll
      for (int f = 0; f < 4; ++f) q0 = MFMA(wb[f], a0[Mt][f], q0, 0, 0, 0);
      u16x4 xo;
#pragma unroll
      for (int q = 0; q < 4; ++q) xo[q] = f2b(fmaxf(q0[q] + b4[q], 0.0f));
      *(u16x4*)(xls + (wbase + Mt * 16 + r16) * XSTR + n * 16 + kg * 4) = xo;
    }
  }
  // publish cell-0 weights
  {
    float4* wd = (float4*)wlds;
#pragma unroll
    for (int r = 0; r < 12; ++r) wd[r * NT + tid] = wst[r];
  }
  __syncthreads();

  // ---- 4 GRU cells ----
#pragma unroll 1
  for (int c = 0; c < 4; ++c) {
    const int co = c * 64;
    const float* bcp = wsB + c * 256;
    bf16x8 ax[2][2], ah[2][2];
#pragma unroll
    for (int Mt = 0; Mt < 2; ++Mt) {
      const unsigned short* xp = xls + (wbase + Mt * 16 + r16) * XSTR + kg * 8;
      ax[Mt][0] = *(const bf16x8*)(xp);
      ax[Mt][1] = *(const bf16x8*)(xp + 32);
      ah[Mt][0] = cvt8(make_float4(hraw[Mt][0].x, hraw[Mt][0].y, hraw[Mt][0].z, hraw[Mt][0].w),
                       make_float4(hraw[Mt][1].x, hraw[Mt][1].y, hraw[Mt][1].z, hraw[Mt][1].w));
      ah[Mt][1] = cvt8(make_float4(hraw[Mt][2].x, hraw[Mt][2].y, hraw[Mt][2].z, hraw[Mt][2].w),
                       make_float4(hraw[Mt][3].x, hraw[Mt][3].y, hraw[Mt][3].z, hraw[Mt][3].w));
    }
    if (c < 3) {
#pragma unroll
      for (int Mt = 0; Mt < 2; ++Mt) {
        const float* hp = memF + (size_t)(m_base + Mt * 16 + r16) * 256 + (c + 1) * 64 + kg * 8;
        hraw[Mt][0] = *(const float4*)(hp);
        hraw[Mt][1] = *(const float4*)(hp + 4);
        hraw[Mt][2] = *(const float4*)(hp + 32);
        hraw[Mt][3] = *(const float4*)(hp + 36);
      }
    }
    const unsigned short* wl = wlds + lane * 8;
#pragma unroll 2
    for (int jt = 0; jt < 4; ++jt) {
      const unsigned short* wjt = wl + jt * 6144;
      bf16x8 xr0 = *(const bf16x8*)(wjt);
      bf16x8 xr1 = *(const bf16x8*)(wjt + 512);
      bf16x8 hr0 = *(const bf16x8*)(wjt + 1024);
      bf16x8 hr1 = *(const bf16x8*)(wjt + 1536);
      bf16x8 xz0 = *(const bf16x8*)(wjt + 2048);
      bf16x8 xz1 = *(const bf16x8*)(wjt + 2560);
      bf16x8 hz0 = *(const bf16x8*)(wjt + 3072);
      bf16x8 hz1 = *(const bf16x8*)(wjt + 3584);
      bf16x8 xn0 = *(const bf16x8*)(wjt + 4096);
      bf16x8 xn1 = *(const bf16x8*)(wjt + 4608);
      bf16x8 hn0 = *(const bf16x8*)(wjt + 5120);
      bf16x8 hn1 = *(const bf16x8*)(wjt + 5632);
      f32x4 sr[2], sz[2], sn[2], tn[2];
#pragma unroll
      for (int Mt = 0; Mt < 2; ++Mt) {
        sr[Mt] = (f32x4)(0.0f); sz[Mt] = (f32x4)(0.0f);
        sn[Mt] = (f32x4)(0.0f); tn[Mt] = (f32x4)(0.0f);
      }
#pragma unroll
      for (int Mt = 0; Mt < 2; ++Mt) {
        sr[Mt] = MFMA(xr0, ax[Mt][0], sr[Mt], 0, 0, 0);
        sr[Mt] = MFMA(xr1, ax[Mt][1], sr[Mt], 0, 0, 0);
        sr[Mt] = MFMA(hr0, ah[Mt][0], sr[Mt], 0, 0, 0);
        sr[Mt] = MFMA(hr1, ah[Mt][1], sr[Mt], 0, 0, 0);
        sz[Mt] = MFMA(xz0, ax[Mt][0], sz[Mt], 0, 0, 0);
        sz[Mt] = MFMA(xz1, ax[Mt][1], sz[Mt], 0, 0, 0);
        sz[Mt] = MFMA(hz0, ah[Mt][0], sz[Mt], 0, 0, 0);
        sz[Mt] = MFMA(hz1, ah[Mt][1], sz[Mt], 0, 0, 0);
        sn[Mt] = MFMA(xn0, ax[Mt][0], sn[Mt], 0, 0, 0);
        sn[Mt] = MFMA(xn1, ax[Mt][1], sn[Mt], 0, 0, 0);
        tn[Mt] = MFMA(hn0, ah[Mt][0], tn[Mt], 0, 0, 0);
        tn[Mt] = MFMA(hn1, ah[Mt][1], tn[Mt], 0, 0, 0);
      }
      const int jb = jt * 16 + kg * 4;
      const f32x4 rb4 = *(const f32x4*)(bcp + jb);
      const f32x4 zb4 = *(const f32x4*)(bcp + 64 + jb);
      const f32x4 ib4 = *(const f32x4*)(bcp + 128 + jb);
      const f32x4 hb4 = *(const f32x4*)(bcp + 192 + jb);
#pragma unroll
      for (int Mt = 0; Mt < 2; ++Mt) {
        const f32x4 ho4 = *(const f32x4*)(memF + (size_t)(m_base + Mt * 16 + r16) * 256 + co + jb);
        f32x4 nhv;
        u16x4 xo;
#pragma unroll
        for (int q = 0; q < 4; ++q) {
          const float rg = sigmoidf_(sr[Mt][q] + rb4[q]);
          const float zg = sigmoidf_(sz[Mt][q] + zb4[q]);
          const float ng = tanhf_((sn[Mt][q] + ib4[q]) + rg * (tn[Mt][q] + hb4[q]));
          const float nh = (1.0f - zg) * ng + zg * ho4[q];
          nhv[q] = nh;
          xo[q] = f2b(nh);
        }
        *(f32x4*)(outMem + (size_t)(m_base + Mt * 16 + r16) * 256 + co + jb) = nhv;
        *(u16x4*)(xls + (wbase + Mt * 16 + r16) * XSTR + jb) = xo;
      }
    }
    if (c < 3) {
      __syncthreads();
      const float4* wsrc = (const float4*)(wsW + (size_t)(c + 1) * 24576);
      float4* wd = (float4*)wlds;
#pragma unroll
      for (int r = 0; r < 12; ++r) wd[r * NT + tid] = wsrc[r * NT + tid];
      __syncthreads();
    }
  }

  // ---- heads: per M-tile ----
  bf16x8 ex[2][2];
#pragma unroll
  for (int Mt = 0; Mt < 2; ++Mt) {
    const unsigned short* xp = xls + (wbase + Mt * 16 + r16) * XSTR + kg * 8;
    ex[Mt][0] = *(const bf16x8*)(xp);
    ex[Mt][1] = *(const bf16x8*)(xp + 32);
  }
  f32x4 ha[2][8];
#pragma unroll
  for (int Mt = 0; Mt < 2; ++Mt)
#pragma unroll
    for (int n = 0; n < 8; ++n) ha[Mt][n] = (f32x4)(0.0f);
#pragma unroll
  for (int n = 0; n < 8; ++n) {
    const unsigned short* wp = wsH + (size_t)(n * 16 + r16) * 64 + kg * 8;
    bf16x8 b0 = *(const bf16x8*)(wp);
    bf16x8 b1 = *(const bf16x8*)(wp + 32);
#pragma unroll
    for (int Mt = 0; Mt < 2; ++Mt) {
      ha[Mt][n] = MFMA(b0, ex[Mt][0], ha[Mt][n], 0, 0, 0);
      ha[Mt][n] = MFMA(b1, ex[Mt][1], ha[Mt][n], 0, 0, 0);
    }
  }
  const int jb0 = kg * 4;
  float l0[2] = {0.0f, 0.0f}, l1[2] = {0.0f, 0.0f}, l2[2] = {0.0f, 0.0f}, vv[2] = {0.0f, 0.0f};
#pragma unroll
  for (int t = 0; t < 4; ++t) {
    const f32x4 ba4 = *(const f32x4*)(ab1 + t * 16 + jb0);
    const f32x4 w0 = *(const f32x4*)(aw2 + t * 16 + jb0);
    const f32x4 w1v = *(const f32x4*)(aw2 + 64 + t * 16 + jb0);
    const f32x4 w2v = *(const f32x4*)(aw2 + 128 + t * 16 + jb0);
    const f32x4 bc4 = *(const f32x4*)(cb1 + t * 16 + jb0);
    const f32x4 wc4 = *(const f32x4*)(cw2 + t * 16 + jb0);
#pragma unroll
    for (int Mt = 0; Mt < 2; ++Mt)
#pragma unroll
      for (int q = 0; q < 4; ++q) {
        const float av = fmaxf(ha[Mt][t][q] + ba4[q], 0.0f);
        const float cv = fmaxf(ha[Mt][t + 4][q] + bc4[q], 0.0f);
        l0[Mt] += av * w0[q]; l1[Mt] += av * w1v[q]; l2[Mt] += av * w2v[q];
        vv[Mt] += cv * wc4[q];
      }
  }
#pragma unroll
  for (int Mt = 0; Mt < 2; ++Mt) {
    l0[Mt] += __shfl_xor(l0[Mt], 16); l0[Mt] += __shfl_xor(l0[Mt], 32);
    l1[Mt] += __shfl_xor(l1[Mt], 16); l1[Mt] += __shfl_xor(l1[Mt], 32);
    l2[Mt] += __shfl_xor(l2[Mt], 16); l2[Mt] += __shfl_xor(l2[Mt], 32);
    vv[Mt] += __shfl_xor(vv[Mt], 16); vv[Mt] += __shfl_xor(vv[Mt], 32);
    if (kg == 0) {
      const int sq = m_base + Mt * 16 + r16;
      const float g0 = l0[Mt] + ab2[0], g1 = l1[Mt] + ab2[1], g2 = l2[Mt] + ab2[2];
      const float mx = fmaxf(g0, fmaxf(g1, g2));
      const float lse = mx + __logf(__expf(g0 - mx) + __expf(g1 - mx) + __expf(g2 - mx));
      out[(size_t)sq * 3 + 0] = g0 - lse;
      out[(size_t)sq * 3 + 1] = g1 - lse;
      out[(size_t)sq * 3 + 2] = g2 - lse;
      out[(size_t)3 * BATCH + sq] = vv[Mt] + cb2[0];
    }
  }
}

extern "C" void kernel_launch(void* const* d_in, const int* in_sizes, int n_in,
                              void* d_out, int out_size, void* d_ws, size_t ws_size,
                              hipStream_t stream) {
  (void)in_sizes; (void)n_in; (void)out_size; (void)ws_size;
  const float* obs = (const float*)d_in[0];
  const float* mem = (const float*)d_in[1];
  const float* w1 = (const float*)d_in[2];
  const float* b1 = (const float*)d_in[3];
  const float* w2 = (const float*)d_in[4];
  const float* b2 = (const float*)d_in[5];
  const float* w3 = (const float*)d_in[6];
  const float* b3 = (const float*)d_in[7];
  const float* gw[16];
  for (int i = 0; i < 16; ++i) gw[i] = (const float*)d_in[8 + i];
  const float* aw1 = (const float*)d_in[24];
  const float* ab1 = (const float*)d_in[25];
  const float* aw2 = (const float*)d_in[26];
  const float* ab2 = (const float*)d_in[27];
  const float* cw1 = (const float*)d_in[28];
  const float* cb1 = (const float*)d_in[29];
  const float* cw2 = (const float*)d_in[30];
  const float* cb2 = (const float*)d_in[31];

  float* out = (float*)d_out;

  unsigned short* c2b = (unsigned short*)d_ws;                 // 128*B u16
  unsigned short* wsW = c2b + (size_t)128 * BATCH;             // 4*24576
  unsigned short* wsH = wsW + 98304;                           // 8192
  unsigned short* wsW3 = wsH + 8192;                           // 8192
  float* wsB = (float*)(wsW3 + 8192);                          // 1024 f32

  hipLaunchKernelGGL(k_front, dim3(1024 + 720), dim3(NT), 0, stream,
                     obs, w1, b1, w2, b2, c2b,
                     gw[0], gw[1], gw[4], gw[5], gw[8], gw[9], gw[12], gw[13],
                     gw[2], gw[6], gw[10], gw[14],
                     gw[3], gw[7], gw[11], gw[15],
                     aw1, cw1, w3, wsW, wsH, wsW3, wsB);
  hipLaunchKernelGGL(k_gru, dim3(BATCH / 128), dim3(NT), 0, stream,
                     c2b, mem, wsW, wsW3, wsB, wsH, b3,
                     ab1, cb1, aw2, ab2, cw2, cb2, out);
}